// Round 11
// baseline (263.075 us; speedup 1.0000x reference)
//
#include <hip/hip_runtime.h>
#include <math.h>

typedef unsigned short u16;
typedef short bf16x8 __attribute__((ext_vector_type(8)));
typedef short bf16x4 __attribute__((ext_vector_type(4)));
typedef float f32x4 __attribute__((ext_vector_type(4)));

#define MFMA(a, b, c) __builtin_amdgcn_mfma_f32_16x16x32_bf16(a, b, c, 0, 0, 0)

// exp2 folded scale: 1/temperature * log2(e) = 0.125 * 1.4426950408889634
#define SCALE_K 0.18033688011112043f

__device__ __forceinline__ float bf2f(u16 v) {
    union { float f; unsigned u; } x;
    x.u = ((unsigned)v) << 16;
    return x.f;
}
__device__ __forceinline__ u16 f2bf(float f) {
    union { float f; unsigned u; } x;
    x.f = f;
    unsigned r = x.u + 0x7FFF + ((x.u >> 16) & 1);
    return (u16)(r >> 16);
}
__device__ __forceinline__ bf16x4 pk4(float a, float b, float c, float d) {
    union { unsigned u[2]; bf16x4 v; } x;
    asm("v_cvt_pk_bf16_f32 %0, %1, %2" : "=v"(x.u[0]) : "v"(a), "v"(b));
    asm("v_cvt_pk_bf16_f32 %0, %1, %2" : "=v"(x.u[1]) : "v"(c), "v"(d));
    return x.v;
}

// ---------------- weight f32 -> bf16 conversion (3 x 512x512) ---------------------------
__global__ __launch_bounds__(256) void cvt_kernel(const float* __restrict__ s0,
                                                  const float* __restrict__ s1,
                                                  const float* __restrict__ s2,
                                                  u16* __restrict__ d0, u16* __restrict__ d1,
                                                  u16* __restrict__ d2) {
    int i = blockIdx.x * 256 + threadIdx.x;  // < 262144
    const float* s = (blockIdx.y == 0) ? s0 : ((blockIdx.y == 1) ? s1 : s2);
    u16* d = (blockIdx.y == 0) ? d0 : ((blockIdx.y == 1) ? d1 : d2);
    d[i] = f2bf(s[i]);
}

// ---------------- x f32 [b][512][3136] -> xT bf16 [b][3136][512] ------------------------
__global__ __launch_bounds__(256) void transpose_kernel(const float* __restrict__ x,
                                                        u16* __restrict__ xT) {
    __shared__ u16 tile[64][65];
    int b = blockIdx.z;
    int n0 = blockIdx.x * 64, c0 = blockIdx.y * 64;
    int j = threadIdx.x & 63, q = threadIdx.x >> 6;
    const float* xb = x + b * 512 * 3136;
#pragma unroll
    for (int it = 0; it < 16; ++it) {
        int r = q * 16 + it;
        tile[r][j] = f2bf(xb[(c0 + r) * 3136 + n0 + j]);
    }
    __syncthreads();
    u16* xTb = xT + b * 3136 * 512;
#pragma unroll
    for (int it = 0; it < 16; ++it) {
        int r = q * 16 + it;
        xTb[(n0 + r) * 512 + c0 + j] = tile[j][r];
    }
}

// ---------------- avgpool 3x3 s2 p1 from xT (channel-contiguous, coalesced) -------------
__global__ __launch_bounds__(256) void pool_kernel(const u16* __restrict__ xT,
                                                   u16* __restrict__ pxT) {
    int n2 = blockIdx.x;        // 0..783
    int b = blockIdx.y;         // 0..1
    int t = threadIdx.x;        // channel c0 = t, c1 = t + 256
    int i = n2 / 28, jj = n2 % 28;
    float s0 = 0.f, s1 = 0.f;
    int cnt = 0;
    const u16* xb = xT + b * 3136 * 512;
#pragma unroll
    for (int dr = 0; dr < 3; dr++) {
        int r = 2 * i - 1 + dr;
        if (r < 0 || r >= 56) continue;
#pragma unroll
        for (int dc = 0; dc < 3; dc++) {
            int cc = 2 * jj - 1 + dc;
            if (cc < 0 || cc >= 56) continue;
            const u16* row = xb + (r * 56 + cc) * 512;
            s0 += bf2f(row[t]);
            s1 += bf2f(row[t + 256]);
            cnt++;
        }
    }
    float invc = 1.0f / (float)cnt;
    u16* op = pxT + (b * 784 + n2) * 512;
    op[t] = f2bf(s0 * invc);
    op[t + 256] = f2bf(s1 * invc);
}

// ---------------- generic 64x64-per-wave MFMA core: D = A * BT^T ------------------------
__device__ __forceinline__ void gemm_core(const u16* __restrict__ A, int lda, int M,
                                          const u16* __restrict__ BT, int ldb, int Ncol,
                                          int K, int row0, int col0, f32x4 acc[4][4]) {
    int lane = threadIdx.x & 63;
    int lr = lane & 15, lg = lane >> 4;
    int ar[4], bc[4];
#pragma unroll
    for (int i = 0; i < 4; i++) {
        int r = row0 + i * 16 + lr;
        ar[i] = (r < M) ? r : (M - 1);
    }
#pragma unroll
    for (int j = 0; j < 4; j++) {
        int cj = col0 + j * 16 + lr;
        bc[j] = (cj < Ncol) ? cj : (Ncol - 1);
    }
    for (int k = 0; k < K; k += 32) {
        int ko = k + lg * 8;
        bf16x8 af[4], bfr[4];
#pragma unroll
        for (int i = 0; i < 4; i++) af[i] = *(const bf16x8*)(A + ar[i] * lda + ko);
#pragma unroll
        for (int j = 0; j < 4; j++) bfr[j] = *(const bf16x8*)(BT + bc[j] * ldb + ko);
#pragma unroll
        for (int i = 0; i < 4; i++)
#pragma unroll
            for (int j = 0; j < 4; j++) acc[i][j] = MFMA(af[i], bfr[j], acc[i][j]);
    }
}

// ---------------- GEMM: D[n][oc] = xT[n][:] . W[oc][:] + bias, scatter to qk[bh][n][64] -
__global__ __launch_bounds__(256, 2) void gemm_qk(const u16* __restrict__ xT,
                                                  const u16* __restrict__ W,
                                                  const float* __restrict__ bias,
                                                  u16* __restrict__ out, int M, int Npad,
                                                  float oscale) {
    int b = blockIdx.z;
    int w = threadIdx.x >> 6;
    int row0 = blockIdx.y * 128 + (w >> 1) * 64;
    int col0 = blockIdx.x * 128 + (w & 1) * 64;
    f32x4 acc[4][4];
#pragma unroll
    for (int i = 0; i < 4; i++)
#pragma unroll
        for (int j = 0; j < 4; j++) acc[i][j] = (f32x4){0.f, 0.f, 0.f, 0.f};
    gemm_core(xT + b * M * 512, 512, M, W, 512, 512, 512, row0, col0, acc);
    int lane = threadIdx.x & 63;
    int lr = lane & 15, lg = lane >> 4;
#pragma unroll
    for (int j = 0; j < 4; j++) {
        int oc = col0 + j * 16 + lr;
        float bs = bias[oc];
        int bh = b * 8 + (oc >> 6), dk = oc & 63;
        u16* op = out + (bh * Npad) * 64 + dk;
#pragma unroll
        for (int i = 0; i < 4; i++) {
#pragma unroll
            for (int r = 0; r < 4; r++) {
                int n = row0 + i * 16 + lg * 4 + r;
                if (n < M) op[n * 64] = f2bf((acc[i][j][r] + bs) * oscale);
                else if (n < Npad) op[n * 64] = 0;  // zero pad rows (masked in attn tail)
            }
        }
    }
}

// ---------------- GEMM: D[oc][n2] = W[oc][:] . pxT[n2][:] + bias, to vt[bh][64][800] ----
__global__ __launch_bounds__(256, 2) void gemm_v(const u16* __restrict__ W,
                                                 const u16* __restrict__ pxT,
                                                 const float* __restrict__ bias,
                                                 u16* __restrict__ vt) {
    int b = blockIdx.z;
    int w = threadIdx.x >> 6;
    int row0 = blockIdx.y * 128 + (w >> 1) * 64;
    int col0 = blockIdx.x * 128 + (w & 1) * 64;
    f32x4 acc[4][4];
#pragma unroll
    for (int i = 0; i < 4; i++)
#pragma unroll
        for (int j = 0; j < 4; j++) acc[i][j] = (f32x4){0.f, 0.f, 0.f, 0.f};
    gemm_core(W, 512, 512, pxT + b * 784 * 512, 512, 784, 512, row0, col0, acc);
    int lane = threadIdx.x & 63;
    int lr = lane & 15, lg = lane >> 4;
#pragma unroll
    for (int i = 0; i < 4; i++) {
#pragma unroll
        for (int r = 0; r < 4; r++) {
            int oc = row0 + i * 16 + lg * 4 + r;
            float bs = bias[oc];
            u16* vp = vt + ((b * 8 + (oc >> 6)) * 64 + (oc & 63)) * 800;
#pragma unroll
            for (int j = 0; j < 4; j++) {
                int n2 = col0 + j * 16 + lr;
                if (n2 < 784) vp[n2] = f2bf(acc[i][j][r] + bs);
                else if (n2 < 800) vp[n2] = 0;  // zero pad: P_pad * 0 = 0 in PV
            }
        }
    }
}

// ---------------- pi stage 1: partial column sums of qt ---------------------------------
__global__ __launch_bounds__(256) void pi_stage1(const u16* __restrict__ qt,
                                                 float* __restrict__ part) {
    __shared__ float red[4][64];
    int chunk = blockIdx.x, bh = blockIdx.y;
    int t = threadIdx.x, dk = t & 63, seg = t >> 6;
    const u16* q = qt + (bh * 3136 + chunk * 112) * 64 + dk;
    float s = 0.f;
    for (int n = seg; n < 112; n += 4) s += bf2f(q[n * 64]);
    red[seg][dk] = s;
    __syncthreads();
    if (t < 64) part[(bh * 28 + chunk) * 64 + t] =
        red[0][t] + red[1][t] + red[2][t] + red[3][t];
}

// ---------------- pi stage 2: combine partials, dot mix_w, softmax ----------------------
__global__ __launch_bounds__(64) void pi_stage2(const float* __restrict__ part,
                                                const float* __restrict__ mix_w,
                                                float* __restrict__ pi) {
    int bh = blockIdx.x, lane = threadIdx.x;
    float bar = 0.f;
#pragma unroll
    for (int c = 0; c < 28; c++) bar += part[(bh * 28 + c) * 64 + lane];
    bar *= (1.0f / 3136.0f);
    float l0 = mix_w[lane] * bar;
    float l1 = mix_w[64 + lane] * bar;
#pragma unroll
    for (int d = 1; d < 64; d <<= 1) {
        l0 += __shfl_xor(l0, d);
        l1 += __shfl_xor(l1, d);
    }
    if (lane == 0) {
        float mx = fmaxf(l0, l1);
        float e0 = __expf(l0 - mx), e1 = __expf(l1 - mx);
        float inv = 1.0f / (e0 + e1);
        pi[bh * 2 + 0] = e0 * inv;
        pi[bh * 2 + 1] = e1 * inv;
    }
}

// ---------------- fused 2-mixture attention: swapped QK^T, P in-register, K=32 PV -------
// Math identical to the round-9/10 PASSING kernels. Round-10 postmortem: occupancy was
// ~1.16 waves/SIMD (allocator burned ~350+ unified VGPR+AGPR/wave with no bound) ->
// zero TLP -> all load/ALU latency exposed. __launch_bounds__(256, 3) forces >=3 waves
// per SIMD (<=~170 regs/wave; live set ~150 fits without hot-loop spills).
__global__ __launch_bounds__(256, 3) void attn_kernel(const u16* __restrict__ qt,
                                                      const u16* __restrict__ kt,
                                                      const u16* __restrict__ vt,
                                                      const float* __restrict__ pi,
                                                      u16* __restrict__ ao) {
    int w = threadIdx.x >> 6, lane = threadIdx.x & 63;
    int lr = lane & 15, lg = lane >> 4;
    int bh = blockIdx.x & 15;   // same head -> same XCD (mod 8): K/V L2-resident
    int xq = blockIdx.x >> 4;   // 0..48
    int qbase = (xq * 4 + w) * 16;
    const u16* qp = qt + (bh * 3136 + qbase) * 64;
    const u16* kbase = kt + bh * 800 * 64 + lr * 64 + lg * 8;
    const u16* vbase = vt + bh * 64 * 800 + lr * 800 + lg * 4;

    bf16x8 qf0 = *(const bf16x8*)(qp + lr * 64 + lg * 8);
    bf16x8 qf1 = *(const bf16x8*)(qp + lr * 64 + 32 + lg * 8);

    const f32x4 z4 = {0.f, 0.f, 0.f, 0.f};
    f32x4 O00 = z4, O01 = z4, O02 = z4, O03 = z4;
    f32x4 O10 = z4, O11 = z4, O12 = z4, O13 = z4;
    float ls0 = 0.f, ls1 = 0.f;

#define LOADK(B, k00, k01, k10, k11)                     \
    k00 = *(const bf16x8*)(kbase + (B) * 64);            \
    k01 = *(const bf16x8*)(kbase + ((B) + 16) * 64);     \
    k10 = *(const bf16x8*)(kbase + (B) * 64 + 32);       \
    k11 = *(const bf16x8*)(kbase + ((B) + 16) * 64 + 32);

#define LOADV(B, va0, va1, va2, va3, vb0, vb1, vb2, vb3) \
    va0 = *(const bf16x4*)(vbase + (B));                 \
    va1 = *(const bf16x4*)(vbase + (B) + 16 * 800);      \
    va2 = *(const bf16x4*)(vbase + (B) + 32 * 800);      \
    va3 = *(const bf16x4*)(vbase + (B) + 48 * 800);      \
    vb0 = *(const bf16x4*)(vbase + (B) + 16);            \
    vb1 = *(const bf16x4*)(vbase + (B) + 16 + 16 * 800); \
    vb2 = *(const bf16x4*)(vbase + (B) + 16 + 32 * 800); \
    vb3 = *(const bf16x4*)(vbase + (B) + 16 + 48 * 800);

#define COMPUTE(k00, k01, k10, k11, va0, va1, va2, va3, vb0, vb1, vb2, vb3, TAIL)  \
    {                                                                              \
        union { bf16x4 h[2]; bf16x8 w8; } vv0, vv1, vv2, vv3, pa;                  \
        vv0.h[0] = va0; vv0.h[1] = vb0;                                            \
        vv1.h[0] = va1; vv1.h[1] = vb1;                                            \
        vv2.h[0] = va2; vv2.h[1] = vb2;                                            \
        vv3.h[0] = va3; vv3.h[1] = vb3;                                            \
        f32x4 s0 = MFMA(k00, qf0, z4);                                             \
        f32x4 s1 = MFMA(k01, qf0, z4);                                             \
        float p0 = __builtin_amdgcn_exp2f(s0[0]);                                  \
        float p1 = __builtin_amdgcn_exp2f(s0[1]);                                  \
        float p2 = __builtin_amdgcn_exp2f(s0[2]);                                  \
        float p3 = __builtin_amdgcn_exp2f(s0[3]);                                  \
        float p4 = __builtin_amdgcn_exp2f(s1[0]);                                  \
        float p5 = __builtin_amdgcn_exp2f(s1[1]);                                  \
        float p6 = __builtin_amdgcn_exp2f(s1[2]);                                  \
        float p7 = __builtin_amdgcn_exp2f(s1[3]);                                  \
        if (TAIL) { p4 = 0.f; p5 = 0.f; p6 = 0.f; p7 = 0.f; }                      \
        ls0 += ((p0 + p1) + (p2 + p3)) + ((p4 + p5) + (p6 + p7));                  \
        pa.h[0] = pk4(p0, p1, p2, p3);                                             \
        pa.h[1] = pk4(p4, p5, p6, p7);                                             \
        O00 = MFMA(pa.w8, vv0.w8, O00);                                            \
        O01 = MFMA(pa.w8, vv1.w8, O01);                                            \
        O02 = MFMA(pa.w8, vv2.w8, O02);                                            \
        O03 = MFMA(pa.w8, vv3.w8, O03);                                            \
        s0 = MFMA(k10, qf1, z4);                                                   \
        s1 = MFMA(k11, qf1, z4);                                                   \
        p0 = __builtin_amdgcn_exp2f(s0[0]);                                        \
        p1 = __builtin_amdgcn_exp2f(s0[1]);                                        \
        p2 = __builtin_amdgcn_exp2f(s0[2]);                                        \
        p3 = __builtin_amdgcn_exp2f(s0[3]);                                        \
        p4 = __builtin_amdgcn_exp2f(s1[0]);                                        \
        p5 = __builtin_amdgcn_exp2f(s1[1]);                                        \
        p6 = __builtin_amdgcn_exp2f(s1[2]);                                        \
        p7 = __builtin_amdgcn_exp2f(s1[3]);                                        \
        if (TAIL) { p4 = 0.f; p5 = 0.f; p6 = 0.f; p7 = 0.f; }                      \
        ls1 += ((p0 + p1) + (p2 + p3)) + ((p4 + p5) + (p6 + p7));                  \
        pa.h[0] = pk4(p0, p1, p2, p3);                                             \
        pa.h[1] = pk4(p4, p5, p6, p7);                                             \
        O10 = MFMA(pa.w8, vv0.w8, O10);                                            \
        O11 = MFMA(pa.w8, vv1.w8, O11);                                            \
        O12 = MFMA(pa.w8, vv2.w8, O12);                                            \
        O13 = MFMA(pa.w8, vv3.w8, O13);                                            \
    }

    bf16x8 kA00, kA01, kA10, kA11, kB00, kB01, kB10, kB11;
    bf16x4 vaA0, vaA1, vaA2, vaA3, vbA0, vbA1, vbA2, vbA3;
    bf16x4 vaB0, vaB1, vaB2, vaB3, vbB0, vbB1, vbB2, vbB3;

    LOADK(0, kA00, kA01, kA10, kA11)
    LOADV(0, vaA0, vaA1, vaA2, vaA3, vbA0, vbA1, vbA2, vbA3)
    for (int c = 0; c < 24; c += 2) {
        int b1 = (c + 1) * 32, b2 = (c + 2) * 32;
        LOADK(b1, kB00, kB01, kB10, kB11)
        LOADV(b1, vaB0, vaB1, vaB2, vaB3, vbB0, vbB1, vbB2, vbB3)
        COMPUTE(kA00, kA01, kA10, kA11, vaA0, vaA1, vaA2, vaA3, vbA0, vbA1, vbA2, vbA3,
                false)
        LOADK(b2, kA00, kA01, kA10, kA11)
        LOADV(b2, vaA0, vaA1, vaA2, vaA3, vbA0, vbA1, vbA2, vbA3)
        COMPUTE(kB00, kB01, kB10, kB11, vaB0, vaB1, vaB2, vaB3, vbB0, vbB1, vbB2, vbB3,
                false)
    }
    COMPUTE(kA00, kA01, kA10, kA11, vaA0, vaA1, vaA2, vaA3, vbA0, vbA1, vbA2, vbA3, true)

    // per-query row-sum is split across the 4 lane groups (same lr) -> xor-reduce
    ls0 += __shfl_xor(ls0, 16);
    ls0 += __shfl_xor(ls0, 32);
    ls1 += __shfl_xor(ls1, 16);
    ls1 += __shfl_xor(ls1, 32);

    float pi0 = pi[bh * 2], pi1 = pi[bh * 2 + 1];
    float inv0[4], inv1[4];
#pragma unroll
    for (int r = 0; r < 4; r++) {
        int n = lg * 4 + r;  // query index; its denom lives in lane n
        inv0[r] = pi0 / __shfl(ls0, n);
        inv1[r] = pi1 / __shfl(ls1, n);
    }
    int b = bh >> 3, h = bh & 7;
    u16* aop = ao + ((b * 3136 + qbase) * 512) + h * 64;
#define STORE(T, OA, OB)                                                    \
    {                                                                       \
        _Pragma("unroll") for (int r = 0; r < 4; r++) {                     \
            int n = lg * 4 + r;                                             \
            aop[n * 512 + (T)*16 + lr] = f2bf(inv0[r] * OA[r] + inv1[r] * OB[r]); \
        }                                                                   \
    }
    STORE(0, O00, O10)
    STORE(1, O01, O11)
    STORE(2, O02, O12)
    STORE(3, O03, O13)
#undef STORE
#undef COMPUTE
#undef LOADV
#undef LOADK
}

// ---------------- final GEMM + BN + residual (f32 residual, FLOAT32 out) ----------------
__global__ __launch_bounds__(256, 2) void gemm_out(const u16* __restrict__ W,
                                                   const u16* __restrict__ aoT,
                                                   const float* __restrict__ gamma,
                                                   const float* __restrict__ beta,
                                                   const float* __restrict__ xres,
                                                   float* __restrict__ out) {
    int b = blockIdx.z;
    int w = threadIdx.x >> 6;
    int row0 = blockIdx.y * 128 + (w >> 1) * 64;
    int col0 = blockIdx.x * 128 + (w & 1) * 64;
    f32x4 acc[4][4];
#pragma unroll
    for (int i = 0; i < 4; i++)
#pragma unroll
        for (int j = 0; j < 4; j++) acc[i][j] = (f32x4){0.f, 0.f, 0.f, 0.f};
    gemm_core(W, 512, 512, aoT + b * 3136 * 512, 512, 3136, 512, row0, col0, acc);
    const float inv = 0.99999500003749969f;  // 1/sqrt(1+1e-5)
    int lane = threadIdx.x & 63;
    int lr = lane & 15, lg = lane >> 4;
#pragma unroll
    for (int i = 0; i < 4; i++) {
#pragma unroll
        for (int r = 0; r < 4; r++) {
            int oc = row0 + i * 16 + lg * 4 + r;
            float g = gamma[oc] * inv;
            float bt = beta[oc];
            const float* xp = xres + (b * 512 + oc) * 3136;
            float* op = out + (b * 512 + oc) * 3136;
#pragma unroll
            for (int j = 0; j < 4; j++) {
                int n = col0 + j * 16 + lr;
                if (n < 3136) op[n] = acc[i][j][r] * g + bt + xp[n];
            }
        }
    }
}

extern "C" void kernel_launch(void* const* d_in, const int* in_sizes, int n_in,
                              void* d_out, int out_size, void* d_ws, size_t ws_size,
                              hipStream_t stream) {
    const float* x = (const float*)d_in[0];
    const float* w_qs = (const float*)d_in[1];
    const float* b_qs = (const float*)d_in[2];
    const float* w_vs = (const float*)d_in[3];
    const float* b_vs = (const float*)d_in[4];
    const float* mix_w = (const float*)d_in[5];
    const float* w_out = (const float*)d_in[6];
    const float* gamma = (const float*)d_in[7];
    const float* beta = (const float*)d_in[8];
    float* out = (float*)d_out;

    char* ws = (char*)d_ws;
    u16* xT = (u16*)(ws + 0);              // 2*3136*512*2 = 6,422,528
    u16* ao = (u16*)(ws + 0);              // ALIAS xT: xT dead before attn writes ao
    u16* pxT = (u16*)(ws + 6422528);       // 2*784*512*2  = 1,605,632
    u16* qt = (u16*)(ws + 8028160);        // 16*3136*64*2 = 6,422,528
    u16* kt = (u16*)(ws + 14450688);       // 16*800*64*2  = 1,638,400
    u16* vt = (u16*)(ws + 16089088);       // 16*64*800*2  = 1,638,400
    u16* wq_b = (u16*)(ws + 17727488);     // 524,288
    u16* wv_b = (u16*)(ws + 18251776);     // 524,288
    u16* wo_b = (u16*)(ws + 18776064);     // 524,288
    float* pi = (float*)(ws + 19300352);   // 128 bytes
    float* part = (float*)(ws + 19300480); // 114,688

    hipLaunchKernelGGL(cvt_kernel, dim3(1024, 3), dim3(256), 0, stream, w_qs, w_vs, w_out,
                       wq_b, wv_b, wo_b);
    hipLaunchKernelGGL(transpose_kernel, dim3(49, 8, 2), dim3(256), 0, stream, x, xT);
    hipLaunchKernelGGL(pool_kernel, dim3(784, 2), dim3(256), 0, stream, xT, pxT);
    hipLaunchKernelGGL(gemm_qk, dim3(4, 25, 2), dim3(256), 0, stream, xT, wq_b, b_qs, qt,
                       3136, 3136, 1.0f);
    hipLaunchKernelGGL(gemm_qk, dim3(4, 7, 2), dim3(256), 0, stream, pxT, wq_b, b_qs, kt,
                       784, 800, SCALE_K);
    hipLaunchKernelGGL(gemm_v, dim3(7, 4, 2), dim3(256), 0, stream, wv_b, pxT, b_vs, vt);
    hipLaunchKernelGGL(pi_stage1, dim3(28, 16), dim3(256), 0, stream, qt, part);
    hipLaunchKernelGGL(pi_stage2, dim3(16), dim3(64), 0, stream, part, mix_w, pi);
    hipLaunchKernelGGL(attn_kernel, dim3(784), dim3(256), 0, stream, qt, kt, vt, pi, ao);
    hipLaunchKernelGGL(gemm_out, dim3(25, 4, 2), dim3(256), 0, stream, wo_b, ao, gamma,
                       beta, x, out);
}

// Round 12
// 229.068 us; speedup vs baseline: 1.1485x; 1.1485x over previous
//
#include <hip/hip_runtime.h>
#include <math.h>

typedef unsigned short u16;
typedef short bf16x8 __attribute__((ext_vector_type(8)));
typedef short bf16x4 __attribute__((ext_vector_type(4)));
typedef float f32x4 __attribute__((ext_vector_type(4)));

#define MFMA(a, b, c) __builtin_amdgcn_mfma_f32_16x16x32_bf16(a, b, c, 0, 0, 0)

// exp2 folded scale: 1/temperature * log2(e) = 0.125 * 1.4426950408889634
#define SCALE_K 0.18033688011112043f

__device__ __forceinline__ float bf2f(u16 v) {
    union { float f; unsigned u; } x;
    x.u = ((unsigned)v) << 16;
    return x.f;
}
__device__ __forceinline__ u16 f2bf(float f) {
    union { float f; unsigned u; } x;
    x.f = f;
    unsigned r = x.u + 0x7FFF + ((x.u >> 16) & 1);
    return (u16)(r >> 16);
}
__device__ __forceinline__ bf16x4 pk4(float a, float b, float c, float d) {
    union { unsigned u[2]; bf16x4 v; } x;
    asm("v_cvt_pk_bf16_f32 %0, %1, %2" : "=v"(x.u[0]) : "v"(a), "v"(b));
    asm("v_cvt_pk_bf16_f32 %0, %1, %2" : "=v"(x.u[1]) : "v"(c), "v"(d));
    return x.v;
}

// ---------------- weight f32 -> bf16 conversion (3 x 512x512) ---------------------------
__global__ __launch_bounds__(256) void cvt_kernel(const float* __restrict__ s0,
                                                  const float* __restrict__ s1,
                                                  const float* __restrict__ s2,
                                                  u16* __restrict__ d0, u16* __restrict__ d1,
                                                  u16* __restrict__ d2) {
    int i = blockIdx.x * 256 + threadIdx.x;  // < 262144
    const float* s = (blockIdx.y == 0) ? s0 : ((blockIdx.y == 1) ? s1 : s2);
    u16* d = (blockIdx.y == 0) ? d0 : ((blockIdx.y == 1) ? d1 : d2);
    d[i] = f2bf(s[i]);
}

// ---------------- x f32 [b][512][3136] -> xT bf16 [b][3136][512] ------------------------
__global__ __launch_bounds__(256) void transpose_kernel(const float* __restrict__ x,
                                                        u16* __restrict__ xT) {
    __shared__ u16 tile[64][65];
    int b = blockIdx.z;
    int n0 = blockIdx.x * 64, c0 = blockIdx.y * 64;
    int j = threadIdx.x & 63, q = threadIdx.x >> 6;
    const float* xb = x + b * 512 * 3136;
#pragma unroll
    for (int it = 0; it < 16; ++it) {
        int r = q * 16 + it;
        tile[r][j] = f2bf(xb[(c0 + r) * 3136 + n0 + j]);
    }
    __syncthreads();
    u16* xTb = xT + b * 3136 * 512;
#pragma unroll
    for (int it = 0; it < 16; ++it) {
        int r = q * 16 + it;
        xTb[(n0 + r) * 512 + c0 + j] = tile[j][r];
    }
}

// ---------------- avgpool 3x3 s2 p1 from xT (channel-contiguous, coalesced) -------------
__global__ __launch_bounds__(256) void pool_kernel(const u16* __restrict__ xT,
                                                   u16* __restrict__ pxT) {
    int n2 = blockIdx.x;        // 0..783
    int b = blockIdx.y;         // 0..1
    int t = threadIdx.x;        // channel c0 = t, c1 = t + 256
    int i = n2 / 28, jj = n2 % 28;
    float s0 = 0.f, s1 = 0.f;
    int cnt = 0;
    const u16* xb = xT + b * 3136 * 512;
#pragma unroll
    for (int dr = 0; dr < 3; dr++) {
        int r = 2 * i - 1 + dr;
        if (r < 0 || r >= 56) continue;
#pragma unroll
        for (int dc = 0; dc < 3; dc++) {
            int cc = 2 * jj - 1 + dc;
            if (cc < 0 || cc >= 56) continue;
            const u16* row = xb + (r * 56 + cc) * 512;
            s0 += bf2f(row[t]);
            s1 += bf2f(row[t + 256]);
            cnt++;
        }
    }
    float invc = 1.0f / (float)cnt;
    u16* op = pxT + (b * 784 + n2) * 512;
    op[t] = f2bf(s0 * invc);
    op[t + 256] = f2bf(s1 * invc);
}

// ---------------- generic 64x64-per-wave MFMA core: D = A * BT^T ------------------------
__device__ __forceinline__ void gemm_core(const u16* __restrict__ A, int lda, int M,
                                          const u16* __restrict__ BT, int ldb, int Ncol,
                                          int K, int row0, int col0, f32x4 acc[4][4]) {
    int lane = threadIdx.x & 63;
    int lr = lane & 15, lg = lane >> 4;
    int ar[4], bc[4];
#pragma unroll
    for (int i = 0; i < 4; i++) {
        int r = row0 + i * 16 + lr;
        ar[i] = (r < M) ? r : (M - 1);
    }
#pragma unroll
    for (int j = 0; j < 4; j++) {
        int cj = col0 + j * 16 + lr;
        bc[j] = (cj < Ncol) ? cj : (Ncol - 1);
    }
    for (int k = 0; k < K; k += 32) {
        int ko = k + lg * 8;
        bf16x8 af[4], bfr[4];
#pragma unroll
        for (int i = 0; i < 4; i++) af[i] = *(const bf16x8*)(A + ar[i] * lda + ko);
#pragma unroll
        for (int j = 0; j < 4; j++) bfr[j] = *(const bf16x8*)(BT + bc[j] * ldb + ko);
#pragma unroll
        for (int i = 0; i < 4; i++)
#pragma unroll
            for (int j = 0; j < 4; j++) acc[i][j] = MFMA(af[i], bfr[j], acc[i][j]);
    }
}

// ---------------- GEMM: D[n][oc] = xT[n][:] . W[oc][:] + bias, scatter to qk[bh][n][64] -
__global__ __launch_bounds__(256) void gemm_qk(const u16* __restrict__ xT,
                                               const u16* __restrict__ W,
                                               const float* __restrict__ bias,
                                               u16* __restrict__ out, int M, int Npad,
                                               float oscale) {
    int b = blockIdx.z;
    int w = threadIdx.x >> 6;
    int row0 = blockIdx.y * 128 + (w >> 1) * 64;
    int col0 = blockIdx.x * 128 + (w & 1) * 64;
    f32x4 acc[4][4];
#pragma unroll
    for (int i = 0; i < 4; i++)
#pragma unroll
        for (int j = 0; j < 4; j++) acc[i][j] = (f32x4){0.f, 0.f, 0.f, 0.f};
    gemm_core(xT + b * M * 512, 512, M, W, 512, 512, 512, row0, col0, acc);
    int lane = threadIdx.x & 63;
    int lr = lane & 15, lg = lane >> 4;
#pragma unroll
    for (int j = 0; j < 4; j++) {
        int oc = col0 + j * 16 + lr;
        float bs = bias[oc];
        int bh = b * 8 + (oc >> 6), dk = oc & 63;
        u16* op = out + (bh * Npad) * 64 + dk;
#pragma unroll
        for (int i = 0; i < 4; i++) {
#pragma unroll
            for (int r = 0; r < 4; r++) {
                int n = row0 + i * 16 + lg * 4 + r;
                if (n < M) op[n * 64] = f2bf((acc[i][j][r] + bs) * oscale);
                else if (n < Npad) op[n * 64] = 0;  // zero pad rows (masked in attn tail)
            }
        }
    }
}

// ---------------- GEMM: D[oc][n2] = W[oc][:] . pxT[n2][:] + bias, to vt[bh][64][800] ----
__global__ __launch_bounds__(256) void gemm_v(const u16* __restrict__ W,
                                              const u16* __restrict__ pxT,
                                              const float* __restrict__ bias,
                                              u16* __restrict__ vt) {
    int b = blockIdx.z;
    int w = threadIdx.x >> 6;
    int row0 = blockIdx.y * 128 + (w >> 1) * 64;
    int col0 = blockIdx.x * 128 + (w & 1) * 64;
    f32x4 acc[4][4];
#pragma unroll
    for (int i = 0; i < 4; i++)
#pragma unroll
        for (int j = 0; j < 4; j++) acc[i][j] = (f32x4){0.f, 0.f, 0.f, 0.f};
    gemm_core(W, 512, 512, pxT + b * 784 * 512, 512, 784, 512, row0, col0, acc);
    int lane = threadIdx.x & 63;
    int lr = lane & 15, lg = lane >> 4;
#pragma unroll
    for (int i = 0; i < 4; i++) {
#pragma unroll
        for (int r = 0; r < 4; r++) {
            int oc = row0 + i * 16 + lg * 4 + r;
            float bs = bias[oc];
            u16* vp = vt + ((b * 8 + (oc >> 6)) * 64 + (oc & 63)) * 800;
#pragma unroll
            for (int j = 0; j < 4; j++) {
                int n2 = col0 + j * 16 + lr;
                if (n2 < 784) vp[n2] = f2bf(acc[i][j][r] + bs);
                else if (n2 < 800) vp[n2] = 0;  // zero pad: P_pad * 0 = 0 in PV
            }
        }
    }
}

// ---------------- pi stage 1: partial column sums of qt ---------------------------------
__global__ __launch_bounds__(256) void pi_stage1(const u16* __restrict__ qt,
                                                 float* __restrict__ part) {
    __shared__ float red[4][64];
    int chunk = blockIdx.x, bh = blockIdx.y;
    int t = threadIdx.x, dk = t & 63, seg = t >> 6;
    const u16* q = qt + (bh * 3136 + chunk * 112) * 64 + dk;
    float s = 0.f;
    for (int n = seg; n < 112; n += 4) s += bf2f(q[n * 64]);
    red[seg][dk] = s;
    __syncthreads();
    if (t < 64) part[(bh * 28 + chunk) * 64 + t] =
        red[0][t] + red[1][t] + red[2][t] + red[3][t];
}

// ---------------- pi stage 2: combine partials, dot mix_w, softmax ----------------------
__global__ __launch_bounds__(64) void pi_stage2(const float* __restrict__ part,
                                                const float* __restrict__ mix_w,
                                                float* __restrict__ pi) {
    int bh = blockIdx.x, lane = threadIdx.x;
    float bar = 0.f;
#pragma unroll
    for (int c = 0; c < 28; c++) bar += part[(bh * 28 + c) * 64 + lane];
    bar *= (1.0f / 3136.0f);
    float l0 = mix_w[lane] * bar;
    float l1 = mix_w[64 + lane] * bar;
#pragma unroll
    for (int d = 1; d < 64; d <<= 1) {
        l0 += __shfl_xor(l0, d);
        l1 += __shfl_xor(l1, d);
    }
    if (lane == 0) {
        float mx = fmaxf(l0, l1);
        float e0 = __expf(l0 - mx), e1 = __expf(l1 - mx);
        float inv = 1.0f / (e0 + e1);
        pi[bh * 2 + 0] = e0 * inv;
        pi[bh * 2 + 1] = e1 * inv;
    }
}

// ---------------- fused 2-mixture attention: key-split across 4 waves -------------------
// Rounds 6-11 postmortem: 784-block grid = 3.06 blocks/CU -> 2-3 resident waves/SIMD ->
// per-wave latency (25 serial tiles) exposed; constant 82-103us across all structures.
// Fix: one block per (bh, qtile) = 3136 blocks; the 4 waves split the 25 key-tiles
// (7/6/6/6 -- no running max, so partial O and partial lsum are plain sums), combine
// via LDS. Wave 3 owns tile 24 (the 16 zero-pad keys get p masked to 0).
__global__ __launch_bounds__(256) void attn_kernel(const u16* __restrict__ qt,
                                                   const u16* __restrict__ kt,
                                                   const u16* __restrict__ vt,
                                                   const float* __restrict__ pi,
                                                   u16* __restrict__ ao) {
    __shared__ float ldsO[8][16][65];  // [w*2+m][q][dv], pad 65 kills write conflicts
    __shared__ float ldsL[8][16];
    int w = threadIdx.x >> 6, lane = threadIdx.x & 63;
    int lr = lane & 15, lg = lane >> 4;
    int bh = blockIdx.x & 15;   // same head -> same XCD (mod 8): K/V L2-resident
    int qti = blockIdx.x >> 4;  // 0..195
    int qbase = qti * 16;
    const u16* qp = qt + (bh * 3136 + qbase) * 64;
    const u16* kbase = kt + bh * 800 * 64 + lr * 64 + lg * 8;
    const u16* vbase = vt + bh * 64 * 800 + lr * 800 + lg * 4;

    bf16x8 qf0 = *(const bf16x8*)(qp + lr * 64 + lg * 8);
    bf16x8 qf1 = *(const bf16x8*)(qp + lr * 64 + 32 + lg * 8);

    const f32x4 z4 = {0.f, 0.f, 0.f, 0.f};
    f32x4 O00 = z4, O01 = z4, O02 = z4, O03 = z4;
    f32x4 O10 = z4, O11 = z4, O12 = z4, O13 = z4;
    float ls0 = 0.f, ls1 = 0.f;

    int start = (w == 0) ? 0 : 1 + 6 * w;  // 0,7,13,19
    int end = start + ((w == 0) ? 7 : 6);
    for (int c = start; c < end; ++c) {
        int base = c * 32;
        bool tail = (c == 24);
        bf16x8 k00 = *(const bf16x8*)(kbase + base * 64);
        bf16x8 k01 = *(const bf16x8*)(kbase + (base + 16) * 64);
        bf16x8 k10 = *(const bf16x8*)(kbase + base * 64 + 32);
        bf16x8 k11 = *(const bf16x8*)(kbase + (base + 16) * 64 + 32);
        bf16x4 va0 = *(const bf16x4*)(vbase + base);
        bf16x4 va1 = *(const bf16x4*)(vbase + base + 16 * 800);
        bf16x4 va2 = *(const bf16x4*)(vbase + base + 32 * 800);
        bf16x4 va3 = *(const bf16x4*)(vbase + base + 48 * 800);
        bf16x4 vb0 = *(const bf16x4*)(vbase + base + 16);
        bf16x4 vb1 = *(const bf16x4*)(vbase + base + 16 + 16 * 800);
        bf16x4 vb2 = *(const bf16x4*)(vbase + base + 16 + 32 * 800);
        bf16x4 vb3 = *(const bf16x4*)(vbase + base + 16 + 48 * 800);
        union { bf16x4 h[2]; bf16x8 w8; } vv0, vv1, vv2, vv3, pa;
        vv0.h[0] = va0; vv0.h[1] = vb0;
        vv1.h[0] = va1; vv1.h[1] = vb1;
        vv2.h[0] = va2; vv2.h[1] = vb2;
        vv3.h[0] = va3; vv3.h[1] = vb3;
        f32x4 s0 = MFMA(k00, qf0, z4);
        f32x4 s1 = MFMA(k01, qf0, z4);
        float p0 = __builtin_amdgcn_exp2f(s0[0]);
        float p1 = __builtin_amdgcn_exp2f(s0[1]);
        float p2 = __builtin_amdgcn_exp2f(s0[2]);
        float p3 = __builtin_amdgcn_exp2f(s0[3]);
        float p4 = __builtin_amdgcn_exp2f(s1[0]);
        float p5 = __builtin_amdgcn_exp2f(s1[1]);
        float p6 = __builtin_amdgcn_exp2f(s1[2]);
        float p7 = __builtin_amdgcn_exp2f(s1[3]);
        if (tail) { p4 = 0.f; p5 = 0.f; p6 = 0.f; p7 = 0.f; }
        ls0 += ((p0 + p1) + (p2 + p3)) + ((p4 + p5) + (p6 + p7));
        pa.h[0] = pk4(p0, p1, p2, p3);
        pa.h[1] = pk4(p4, p5, p6, p7);
        O00 = MFMA(pa.w8, vv0.w8, O00);
        O01 = MFMA(pa.w8, vv1.w8, O01);
        O02 = MFMA(pa.w8, vv2.w8, O02);
        O03 = MFMA(pa.w8, vv3.w8, O03);
        s0 = MFMA(k10, qf1, z4);
        s1 = MFMA(k11, qf1, z4);
        p0 = __builtin_amdgcn_exp2f(s0[0]);
        p1 = __builtin_amdgcn_exp2f(s0[1]);
        p2 = __builtin_amdgcn_exp2f(s0[2]);
        p3 = __builtin_amdgcn_exp2f(s0[3]);
        p4 = __builtin_amdgcn_exp2f(s1[0]);
        p5 = __builtin_amdgcn_exp2f(s1[1]);
        p6 = __builtin_amdgcn_exp2f(s1[2]);
        p7 = __builtin_amdgcn_exp2f(s1[3]);
        if (tail) { p4 = 0.f; p5 = 0.f; p6 = 0.f; p7 = 0.f; }
        ls1 += ((p0 + p1) + (p2 + p3)) + ((p4 + p5) + (p6 + p7));
        pa.h[0] = pk4(p0, p1, p2, p3);
        pa.h[1] = pk4(p4, p5, p6, p7);
        O10 = MFMA(pa.w8, vv0.w8, O10);
        O11 = MFMA(pa.w8, vv1.w8, O11);
        O12 = MFMA(pa.w8, vv2.w8, O12);
        O13 = MFMA(pa.w8, vv3.w8, O13);
    }

    // per-query partial row-sum: combine the 4 lane groups of this wave
    ls0 += __shfl_xor(ls0, 16);
    ls0 += __shfl_xor(ls0, 32);
    ls1 += __shfl_xor(ls1, 16);
    ls1 += __shfl_xor(ls1, 32);
    if (lane < 16) {
        ldsL[w * 2 + 0][lr] = ls0;
        ldsL[w * 2 + 1][lr] = ls1;
    }
    // partial O -> LDS: lane (lr,lg) holds q=lg*4+r, dv=t*16+lr
#define PUTO(T, OA, OB)                              \
    {                                                \
        _Pragma("unroll") for (int r = 0; r < 4; r++) { \
            ldsO[w * 2 + 0][lg * 4 + r][(T)*16 + lr] = OA[r]; \
            ldsO[w * 2 + 1][lg * 4 + r][(T)*16 + lr] = OB[r]; \
        }                                            \
    }
    PUTO(0, O00, O10)
    PUTO(1, O01, O11)
    PUTO(2, O02, O12)
    PUTO(3, O03, O13)
#undef PUTO
    __syncthreads();

    // combine 4 wave-partials; scale; store. thread t -> col t&63, rows (t>>6)*4 + i
    float pi0 = pi[bh * 2], pi1 = pi[bh * 2 + 1];
    int col = threadIdx.x & 63, rg = threadIdx.x >> 6;
    int b = bh >> 3, h = bh & 7;
    u16* aop = ao + ((b * 3136 + qbase) * 512) + h * 64;
#pragma unroll
    for (int i = 0; i < 4; i++) {
        int q = rg * 4 + i;
        float l0 = ldsL[0][q] + ldsL[2][q] + ldsL[4][q] + ldsL[6][q];
        float l1 = ldsL[1][q] + ldsL[3][q] + ldsL[5][q] + ldsL[7][q];
        float o0 = ldsO[0][q][col] + ldsO[2][q][col] + ldsO[4][q][col] + ldsO[6][q][col];
        float o1 = ldsO[1][q][col] + ldsO[3][q][col] + ldsO[5][q][col] + ldsO[7][q][col];
        aop[q * 512 + col] = f2bf((pi0 / l0) * o0 + (pi1 / l1) * o1);
    }
}

// ---------------- final GEMM + BN + residual (f32 residual, FLOAT32 out) ----------------
__global__ __launch_bounds__(256) void gemm_out(const u16* __restrict__ W,
                                                const u16* __restrict__ aoT,
                                                const float* __restrict__ gamma,
                                                const float* __restrict__ beta,
                                                const float* __restrict__ xres,
                                                float* __restrict__ out) {
    int b = blockIdx.z;
    int w = threadIdx.x >> 6;
    int row0 = blockIdx.y * 128 + (w >> 1) * 64;
    int col0 = blockIdx.x * 128 + (w & 1) * 64;
    f32x4 acc[4][4];
#pragma unroll
    for (int i = 0; i < 4; i++)
#pragma unroll
        for (int j = 0; j < 4; j++) acc[i][j] = (f32x4){0.f, 0.f, 0.f, 0.f};
    gemm_core(W, 512, 512, aoT + b * 3136 * 512, 512, 3136, 512, row0, col0, acc);
    const float inv = 0.99999500003749969f;  // 1/sqrt(1+1e-5)
    int lane = threadIdx.x & 63;
    int lr = lane & 15, lg = lane >> 4;
#pragma unroll
    for (int i = 0; i < 4; i++) {
#pragma unroll
        for (int r = 0; r < 4; r++) {
            int oc = row0 + i * 16 + lg * 4 + r;
            float g = gamma[oc] * inv;
            float bt = beta[oc];
            const float* xp = xres + (b * 512 + oc) * 3136;
            float* op = out + (b * 512 + oc) * 3136;
#pragma unroll
            for (int j = 0; j < 4; j++) {
                int n = col0 + j * 16 + lr;
                if (n < 3136) op[n] = acc[i][j][r] * g + bt + xp[n];
            }
        }
    }
}

extern "C" void kernel_launch(void* const* d_in, const int* in_sizes, int n_in,
                              void* d_out, int out_size, void* d_ws, size_t ws_size,
                              hipStream_t stream) {
    const float* x = (const float*)d_in[0];
    const float* w_qs = (const float*)d_in[1];
    const float* b_qs = (const float*)d_in[2];
    const float* w_vs = (const float*)d_in[3];
    const float* b_vs = (const float*)d_in[4];
    const float* mix_w = (const float*)d_in[5];
    const float* w_out = (const float*)d_in[6];
    const float* gamma = (const float*)d_in[7];
    const float* beta = (const float*)d_in[8];
    float* out = (float*)d_out;

    char* ws = (char*)d_ws;
    u16* xT = (u16*)(ws + 0);              // 2*3136*512*2 = 6,422,528
    u16* ao = (u16*)(ws + 0);              // ALIAS xT: xT dead before attn writes ao
    u16* pxT = (u16*)(ws + 6422528);       // 2*784*512*2  = 1,605,632
    u16* qt = (u16*)(ws + 8028160);        // 16*3136*64*2 = 6,422,528
    u16* kt = (u16*)(ws + 14450688);       // 16*800*64*2  = 1,638,400
    u16* vt = (u16*)(ws + 16089088);       // 16*64*800*2  = 1,638,400
    u16* wq_b = (u16*)(ws + 17727488);     // 524,288
    u16* wv_b = (u16*)(ws + 18251776);     // 524,288
    u16* wo_b = (u16*)(ws + 18776064);     // 524,288
    float* pi = (float*)(ws + 19300352);   // 128 bytes
    float* part = (float*)(ws + 19300480); // 114,688

    hipLaunchKernelGGL(cvt_kernel, dim3(1024, 3), dim3(256), 0, stream, w_qs, w_vs, w_out,
                       wq_b, wv_b, wo_b);
    hipLaunchKernelGGL(transpose_kernel, dim3(49, 8, 2), dim3(256), 0, stream, x, xT);
    hipLaunchKernelGGL(pool_kernel, dim3(784, 2), dim3(256), 0, stream, xT, pxT);
    hipLaunchKernelGGL(gemm_qk, dim3(4, 25, 2), dim3(256), 0, stream, xT, wq_b, b_qs, qt,
                       3136, 3136, 1.0f);
    hipLaunchKernelGGL(gemm_qk, dim3(4, 7, 2), dim3(256), 0, stream, pxT, wq_b, b_qs, kt,
                       784, 800, SCALE_K);
    hipLaunchKernelGGL(gemm_v, dim3(7, 4, 2), dim3(256), 0, stream, wv_b, pxT, b_vs, vt);
    hipLaunchKernelGGL(pi_stage1, dim3(28, 16), dim3(256), 0, stream, qt, part);
    hipLaunchKernelGGL(pi_stage2, dim3(16), dim3(64), 0, stream, part, mix_w, pi);
    hipLaunchKernelGGL(attn_kernel, dim3(3136), dim3(256), 0, stream, qt, kt, vt, pi, ao);
    hipLaunchKernelGGL(gemm_out, dim3(25, 4, 2), dim3(256), 0, stream, wo_b, ao, gamma,
                       beta, x, out);
}